// Round 7
// baseline (296.875 us; speedup 1.0000x reference)
//
#include <hip/hip_runtime.h>
#include <hip/hip_bf16.h>

#define INF_F (__builtin_inff())

typedef __attribute__((ext_vector_type(8))) short bf16x8;
typedef __attribute__((ext_vector_type(4))) float f32x4;

__device__ __forceinline__ unsigned short f2bf(float f) {
  __hip_bfloat16 h = __float2bfloat16(f);
  return __builtin_bit_cast(unsigned short, h);
}
__device__ __forceinline__ float bf2f(unsigned short u) {
  return __uint_as_float((unsigned)u << 16);
}

// ---------------------------------------------------------------------------
// B=4, N=16384, S=4096, D1=128, D2=256, MLP=(256,128). M = B*N = 65536.
// X: [65536][384] bf16 (cols 0..127 = points1^T, 128..383 = interp)
// h1T: [65536][256] bf16 ; out2T: [65536][128] fp32.
// GEMMs: D[c][n] = W[c][k] * X[n][k] via mfma_f32_16x16x32_bf16.
// ---------------------------------------------------------------------------

// points2 [B][256][4096] -> p2t [B][4096][256] fp32 (coalesced gather rows)
__global__ __launch_bounds__(256) void transpose_k(const float* __restrict__ in,
                                                   float* __restrict__ out) {
  __shared__ float tile[32][33];
  int b = blockIdx.z;
  int s0 = blockIdx.x * 32;
  int k0 = blockIdx.y * 32;
  int tx = threadIdx.x, ty = threadIdx.y;  // 32 x 8
  const float* src = in + ((size_t)b * 256 + k0) * 4096 + s0;
  for (int r = ty; r < 32; r += 8) tile[r][tx] = src[(size_t)r * 4096 + tx];
  __syncthreads();
  float* dst = out + ((size_t)b * 4096 + s0) * 256 + k0;
  for (int r = ty; r < 32; r += 8) dst[(size_t)r * 256 + tx] = tile[tx][r];
}

// p1 [B][128][16384] fp32 -> X[b*16384+n][0..127] bf16 (transposed)
__global__ __launch_bounds__(256) void p1t_k(const float* __restrict__ p1,
                                             unsigned short* __restrict__ X) {
  __shared__ float tile[32][33];
  int b = blockIdx.z;
  int n0 = blockIdx.x * 32;
  int c0 = blockIdx.y * 32;
  int tx = threadIdx.x, ty = threadIdx.y;
  const float* src = p1 + ((size_t)b * 128 + c0) * 16384 + n0;
  for (int r = ty; r < 32; r += 8) tile[r][tx] = src[(size_t)r * 16384 + tx];
  __syncthreads();
  for (int r = ty; r < 32; r += 8)
    X[((size_t)(b * 16384 + n0 + r)) * 384 + c0 + tx] = f2bf(tile[tx][r]);
}

// w1 [256][384], w2 [128][256] fp32 -> bf16 copies (same layout)
__global__ __launch_bounds__(256) void wcvt_k(const float* __restrict__ w1,
                                              const float* __restrict__ w2,
                                              unsigned short* __restrict__ w1b,
                                              unsigned short* __restrict__ w2b) {
  int id = blockIdx.x * 256 + threadIdx.x;
  if (id < 98304) w1b[id] = f2bf(w1[id]);
  else w2b[id - 98304] = f2bf(w2[id - 98304]);
}

// 3-NN stage 1. 512 blocks = 128 query-chunks (512 q) x 4 S-quarters (1024
// src, 16KB LDS). 256 thr x 2 queries/thread: one broadcast ds_read_b128
// feeds 128 pairs (R6 bound was LDS-pipe issue: ~12cyc per b128 per CU).
// Validity folded into staged |p|^2 (3e38 if batch-id != common). Branchy
// top-3 insert, strict < + ascending s = top_k tie order. Per-thread exact
// slow path if its id != common (never taken on this data).
__global__ __launch_bounds__(256) void knn_k(const float* __restrict__ xyz1,
                                             const float* __restrict__ xyz2,
                                             const int* __restrict__ idx1,
                                             const int* __restrict__ idx2,
                                             float* __restrict__ rec) {
  __shared__ float4 sP[1024];  // 16KB
  int bid = blockIdx.x;
  int nchunk = bid >> 2, sq = bid & 3;
  int b = nchunk >> 5;
  int n0 = (nchunk & 31) * 512;  // offset within batch
  int t = threadIdx.x;
  int common = idx1[b * 16384 + n0];
  int sbase = sq << 10;
  for (int s = t; s < 1024; s += 256) {
    int gs = sbase + s;
    float x = xyz2[(b * 3 + 0) * 4096 + gs];
    float y = xyz2[(b * 3 + 1) * 4096 + gs];
    float z = xyz2[(b * 3 + 2) * 4096 + gs];
    float w = fmaf(x, x, fmaf(y, y, z * z));
    int sid = idx2[b * 4096 + gs];
    w = (sid == common) ? w : 3e38f;  // invalid -> d ~ 3e38 > BIG -> weight 0
    sP[s] = make_float4(x, y, z, w);
  }
  __syncthreads();
  int nla = n0 + t, nlb = n0 + 256 + t;  // two queries per thread
  float pxa = xyz1[(b * 3 + 0) * 16384 + nla];
  float pya = xyz1[(b * 3 + 1) * 16384 + nla];
  float pza = xyz1[(b * 3 + 2) * 16384 + nla];
  float pxb = xyz1[(b * 3 + 0) * 16384 + nlb];
  float pyb = xyz1[(b * 3 + 1) * 16384 + nlb];
  float pzb = xyz1[(b * 3 + 2) * 16384 + nlb];
  int ida = idx1[b * 16384 + nla];
  int idb = idx1[b * 16384 + nlb];
  float pna = fmaf(pxa, pxa, fmaf(pya, pya, pza * pza));
  float pnb = fmaf(pxb, pxb, fmaf(pyb, pyb, pzb * pzb));
  float e0a = INF_F, e1a = INF_F, e2a = INF_F;
  float e0b = INF_F, e1b = INF_F, e2b = INF_F;
  int j0a = 0, j1a = 0, j2a = 0, j0b = 0, j1b = 0, j2b = 0;
#pragma unroll 4
  for (int s = 0; s < 1024; ++s) {
    float4 p = sP[s];  // wave-uniform addr -> LDS broadcast, conflict-free
    float dota = fmaf(pxa, p.x, fmaf(pya, p.y, pza * p.z));
    float da = fmaf(-2.f, dota, pna + p.w);  // ref formula |a|^2+|b|^2-2ab
    float dotb = fmaf(pxb, p.x, fmaf(pyb, p.y, pzb * p.z));
    float db = fmaf(-2.f, dotb, pnb + p.w);
    if (da < e2a) {  // rare past warmup
      int sj = sbase + s;
      bool l0 = da < e0a, l1 = da < e1a;
      e2a = l1 ? e1a : da;           j2a = l1 ? j1a : sj;
      e1a = l0 ? e0a : (l1 ? da : e1a); j1a = l0 ? j0a : (l1 ? sj : j1a);
      e0a = l0 ? da : e0a;           j0a = l0 ? sj : j0a;
    }
    if (db < e2b) {
      int sj = sbase + s;
      bool l0 = db < e0b, l1 = db < e1b;
      e2b = l1 ? e1b : db;           j2b = l1 ? j1b : sj;
      e1b = l0 ? e0b : (l1 ? db : e1b); j1b = l0 ? j0b : (l1 ? sj : j1b);
      e0b = l0 ? db : e0b;           j0b = l0 ? sj : j0b;
    }
  }
  if (__builtin_expect(ida != common, 0)) {  // exact general-idx fallback (a)
    e0a = e1a = e2a = INF_F; j0a = j1a = j2a = 0;
    for (int s = 0; s < 1024; ++s) {
      int gs = sbase + s;
      float x = xyz2[(b * 3 + 0) * 4096 + gs];
      float y = xyz2[(b * 3 + 1) * 4096 + gs];
      float z = xyz2[(b * 3 + 2) * 4096 + gs];
      float w = fmaf(x, x, fmaf(y, y, z * z));
      float d = fmaf(-2.f, fmaf(pxa, x, fmaf(pya, y, pza * z)), pna + w);
      d = (idx2[b * 4096 + gs] == ida) ? d : INF_F;
      if (d < e2a) {
        bool l0 = d < e0a, l1 = d < e1a;
        e2a = l1 ? e1a : d; j2a = l1 ? j1a : gs;
        e1a = l0 ? e0a : (l1 ? d : e1a); j1a = l0 ? j0a : (l1 ? gs : j1a);
        e0a = l0 ? d : e0a; j0a = l0 ? gs : j0a;
      }
    }
  }
  if (__builtin_expect(idb != common, 0)) {  // exact general-idx fallback (b)
    e0b = e1b = e2b = INF_F; j0b = j1b = j2b = 0;
    for (int s = 0; s < 1024; ++s) {
      int gs = sbase + s;
      float x = xyz2[(b * 3 + 0) * 4096 + gs];
      float y = xyz2[(b * 3 + 1) * 4096 + gs];
      float z = xyz2[(b * 3 + 2) * 4096 + gs];
      float w = fmaf(x, x, fmaf(y, y, z * z));
      float d = fmaf(-2.f, fmaf(pxb, x, fmaf(pyb, y, pzb * z)), pnb + w);
      d = (idx2[b * 4096 + gs] == idb) ? d : INF_F;
      if (d < e2b) {
        bool l0 = d < e0b, l1 = d < e1b;
        e2b = l1 ? e1b : d; j2b = l1 ? j1b : gs;
        e1b = l0 ? e0b : (l1 ? d : e1b); j1b = l0 ? j0b : (l1 ? gs : j1b);
        e0b = l0 ? d : e0b; j0b = l0 ? gs : j0b;
      }
    }
  }
  {
    float* r = &rec[(((size_t)(b * 16384 + nla)) * 4 + sq) * 6];
    r[0] = e0a; r[1] = e1a; r[2] = e2a;
    ((int*)r)[3] = j0a; ((int*)r)[4] = j1a; ((int*)r)[5] = j2a;
  }
  {
    float* r = &rec[(((size_t)(b * 16384 + nlb)) * 4 + sq) * 6];
    r[0] = e0b; r[1] = e1b; r[2] = e2b;
    ((int*)r)[3] = j0b; ((int*)r)[4] = j1b; ((int*)r)[5] = j2b;
  }
}

// 3-NN stage 2: merge 4 S-quarter records (ascending chunk order, lex (d,idx)
// = exact top_k tie semantics), compute inverse-distance weights.
__global__ __launch_bounds__(256) void knnmerge_k(const float* __restrict__ rec,
                                                  int* __restrict__ idx3,
                                                  float* __restrict__ wgt) {
  int i = blockIdx.x * 256 + threadIdx.x;  // 65536 queries
  const float* rA = &rec[(size_t)i * 24];
  const int* iA = (const int*)rA;
  float e0 = rA[0], e1 = rA[1], e2 = rA[2];
  int j0 = iA[3], j1 = iA[4], j2 = iA[5];
#pragma unroll
  for (int c = 1; c < 4; ++c) {
#pragma unroll
    for (int w = 0; w < 3; ++w) {
      float d = rA[c * 6 + w];
      int sj = iA[c * 6 + 3 + w];
      bool l0 = (d < e0) || (d == e0 && sj < j0);
      bool l1 = (d < e1) || (d == e1 && sj < j1);
      bool l2 = (d < e2) || (d == e2 && sj < j2);
      e2 = l1 ? e1 : (l2 ? d : e2);
      j2 = l1 ? j1 : (l2 ? sj : j2);
      e1 = l0 ? e0 : (l1 ? d : e1);
      j1 = l0 ? j0 : (l1 ? sj : j1);
      e0 = l0 ? d : e0;
      j0 = l0 ? sj : j0;
    }
  }
  float r0 = 1.f / (e0 + 1e-8f);
  float r1 = 1.f / (e1 + 1e-8f);
  float r2 = 1.f / (e2 + 1e-8f);
  float rs = r0 + r1 + r2;
  float w0 = (e0 > 1e8f) ? 0.f : r0 / rs;  // ref: where(d3>BIG,0)+nan_to_num
  float w1 = (e1 > 1e8f) ? 0.f : r1 / rs;
  float w2 = (e2 > 1e8f) ? 0.f : r2 / rs;
  idx3[(size_t)i * 3 + 0] = j0; idx3[(size_t)i * 3 + 1] = j1; idx3[(size_t)i * 3 + 2] = j2;
  wgt[(size_t)i * 3 + 0] = w0;  wgt[(size_t)i * 3 + 1] = w1;  wgt[(size_t)i * 3 + 2] = w2;
}

// interp -> X[i][128+k] bf16
__global__ __launch_bounds__(256) void interp_k(const float* __restrict__ p2t,
                                                const int* __restrict__ idx3,
                                                const float* __restrict__ wgt,
                                                unsigned short* __restrict__ X) {
  int i0 = blockIdx.x * 128;
  int b = i0 >> 14;
  int k = threadIdx.x;
  const float* base = p2t + (size_t)b * 4096 * 256;
#pragma unroll 2
  for (int ii = 0; ii < 128; ++ii) {
    int i = i0 + ii;
    int id0 = idx3[i * 3 + 0], id1 = idx3[i * 3 + 1], id2 = idx3[i * 3 + 2];
    float w0 = wgt[i * 3 + 0], w1v = wgt[i * 3 + 1], w2v = wgt[i * 3 + 2];
    float v = w0 * base[id0 * 256 + k];
    v = fmaf(w1v, base[id1 * 256 + k], v);
    v = fmaf(w2v, base[id2 * 256 + k], v);
    X[(size_t)i * 384 + 128 + k] = f2bf(v);
  }
}

// GEMM1 (MFMA): h1T[n][c] = sum_k w1[c][k] X[n][k]. 128x128 tile, BK=32,
// K=384. grid (512, 2).
__global__ __launch_bounds__(256) void gemm1_k(const unsigned short* __restrict__ X,
                                               const unsigned short* __restrict__ Wb,
                                               unsigned short* __restrict__ h1T) {
  __shared__ unsigned short sW[128][40];
  __shared__ unsigned short sX[128][40];
  int t = threadIdx.x;
  int i0 = blockIdx.x * 128;
  int c0 = blockIdx.y * 128;
  int w = t >> 6, lane = t & 63;
  int wc = (w & 1) * 64, wn = (w >> 1) * 64;
  int l15 = lane & 15, g = lane >> 4;
  f32x4 acc[4][4];
#pragma unroll
  for (int a = 0; a < 4; ++a)
#pragma unroll
    for (int bq = 0; bq < 4; ++bq) acc[a][bq] = (f32x4)0.f;
  int sr = t & 127, sh = t >> 7;
  for (int kc = 0; kc < 12; ++kc) {
    int k0 = kc * 32;
    __syncthreads();
    {
      const uint4* gw = (const uint4*)&Wb[(size_t)(c0 + sr) * 384 + k0 + sh * 16];
      uint4 v0 = gw[0], v1 = gw[1];
      *(uint4*)&sW[sr][sh * 16] = v0;
      *(uint4*)&sW[sr][sh * 16 + 8] = v1;
      const uint4* gx = (const uint4*)&X[(size_t)(i0 + sr) * 384 + k0 + sh * 16];
      uint4 x0 = gx[0], x1 = gx[1];
      *(uint4*)&sX[sr][sh * 16] = x0;
      *(uint4*)&sX[sr][sh * 16 + 8] = x1;
    }
    __syncthreads();
    bf16x8 a[4], b[4];
#pragma unroll
    for (int tm = 0; tm < 4; ++tm)
      a[tm] = *(const bf16x8*)&sW[wc + tm * 16 + l15][g * 8];
#pragma unroll
    for (int tn = 0; tn < 4; ++tn)
      b[tn] = *(const bf16x8*)&sX[wn + tn * 16 + l15][g * 8];
#pragma unroll
    for (int tm = 0; tm < 4; ++tm)
#pragma unroll
      for (int tn = 0; tn < 4; ++tn)
        acc[tm][tn] = __builtin_amdgcn_mfma_f32_16x16x32_bf16(a[tm], b[tn], acc[tm][tn], 0, 0, 0);
  }
#pragma unroll
  for (int tm = 0; tm < 4; ++tm)
#pragma unroll
    for (int tn = 0; tn < 4; ++tn) {
      int c = c0 + wc + tm * 16 + g * 4;
      int n = i0 + wn + tn * 16 + l15;
      f32x4 v = acc[tm][tn];
      ushort4 o;
      o.x = f2bf(v[0]); o.y = f2bf(v[1]); o.z = f2bf(v[2]); o.w = f2bf(v[3]);
      *(ushort4*)&h1T[(size_t)n * 256 + c] = o;
    }
}

// BN1 stats over h1T bf16 [65536][256]
__global__ __launch_bounds__(256) void bnstats1_k(const unsigned short* __restrict__ h,
                                                  float* __restrict__ part) {
  int t = threadIdx.x, q = t & 63, ro = t >> 6;
  int r0 = blockIdx.x * 256;
  float s0 = 0, s1 = 0, s2 = 0, s3 = 0, q0 = 0, q1 = 0, q2 = 0, q3 = 0;
  for (int it = 0; it < 64; ++it) {
    size_t r = r0 + it * 4 + ro;
    ushort4 v = *(const ushort4*)&h[r * 256 + q * 4];
    float f0 = bf2f(v.x), f1 = bf2f(v.y), f2 = bf2f(v.z), f3 = bf2f(v.w);
    s0 += f0; q0 += f0 * f0;
    s1 += f1; q1 += f1 * f1;
    s2 += f2; q2 += f2 * f2;
    s3 += f3; q3 += f3 * f3;
  }
  __shared__ float sm[256][8];
  sm[t][0] = s0; sm[t][1] = s1; sm[t][2] = s2; sm[t][3] = s3;
  sm[t][4] = q0; sm[t][5] = q1; sm[t][6] = q2; sm[t][7] = q3;
  __syncthreads();
  if (t < 64) {
#pragma unroll
    for (int j = 1; j < 4; ++j)
#pragma unroll
      for (int e = 0; e < 8; ++e) sm[t][e] += sm[t + 64 * j][e];
#pragma unroll
    for (int i = 0; i < 4; ++i) {
      part[((size_t)blockIdx.x * 256 + t * 4 + i) * 2 + 0] = sm[t][i];
      part[((size_t)blockIdx.x * 256 + t * 4 + i) * 2 + 1] = sm[t][4 + i];
    }
  }
}

// BN2 stats over out2T fp32 [65536][128]
__global__ __launch_bounds__(256) void bnstats2_k(const float* __restrict__ o2,
                                                  float* __restrict__ part) {
  int t = threadIdx.x, q = t & 31, ro = t >> 5;
  int r0 = blockIdx.x * 256;
  float s0 = 0, s1 = 0, s2 = 0, s3 = 0, q0 = 0, q1 = 0, q2 = 0, q3 = 0;
  for (int it = 0; it < 32; ++it) {
    size_t r = r0 + it * 8 + ro;
    float4 v = *(const float4*)&o2[r * 128 + q * 4];
    s0 += v.x; q0 += v.x * v.x;
    s1 += v.y; q1 += v.y * v.y;
    s2 += v.z; q2 += v.z * v.z;
    s3 += v.w; q3 += v.w * v.w;
  }
  __shared__ float sm[256][8];
  sm[t][0] = s0; sm[t][1] = s1; sm[t][2] = s2; sm[t][3] = s3;
  sm[t][4] = q0; sm[t][5] = q1; sm[t][6] = q2; sm[t][7] = q3;
  __syncthreads();
  if (t < 32) {
#pragma unroll
    for (int j = 1; j < 8; ++j)
#pragma unroll
      for (int e = 0; e < 8; ++e) sm[t][e] += sm[t + 32 * j][e];
#pragma unroll
    for (int i = 0; i < 4; ++i) {
      part[((size_t)blockIdx.x * 128 + t * 4 + i) * 2 + 0] = sm[t][i];
      part[((size_t)blockIdx.x * 128 + t * 4 + i) * 2 + 1] = sm[t][4 + i];
    }
  }
}

// fold partials -> per-channel a*x + c
template <int C>
__global__ __launch_bounds__(256) void bnfold_k(const float* __restrict__ part,
                                                const float* __restrict__ g,
                                                const float* __restrict__ be,
                                                float* __restrict__ A,
                                                float* __restrict__ Cc) {
  int c = threadIdx.x;
  if (c >= C) return;
  float s1 = 0.f, s2 = 0.f;
  for (int b = 0; b < 256; ++b) {
    s1 += part[((size_t)b * C + c) * 2 + 0];
    s2 += part[((size_t)b * C + c) * 2 + 1];
  }
  float mean = s1 * (1.f / 65536.f);
  float var = s2 * (1.f / 65536.f) - mean * mean;  // biased, as torch BN
  float a = g[c] * rsqrtf(var + 1e-5f);
  A[c] = a;
  Cc[c] = be[c] - mean * a;
}

// GEMM2 (MFMA) with fused BN1+ReLU on staging: out2T[n][c2] =
// sum_k w2[c2][k] relu(a1[k]*h1T[n][k]+c1[k]). K=256. grid (512).
__global__ __launch_bounds__(256) void gemm2_k(const unsigned short* __restrict__ h1T,
                                               const unsigned short* __restrict__ Wb,
                                               const float* __restrict__ A,
                                               const float* __restrict__ C,
                                               float* __restrict__ o2) {
  __shared__ unsigned short sW[128][40];
  __shared__ unsigned short sX[128][40];
  int t = threadIdx.x;
  int i0 = blockIdx.x * 128;
  int w = t >> 6, lane = t & 63;
  int wc = (w & 1) * 64, wn = (w >> 1) * 64;
  int l15 = lane & 15, g = lane >> 4;
  f32x4 acc[4][4];
#pragma unroll
  for (int a = 0; a < 4; ++a)
#pragma unroll
    for (int bq = 0; bq < 4; ++bq) acc[a][bq] = (f32x4)0.f;
  int sr = t & 127, sh = t >> 7;
  for (int kc = 0; kc < 8; ++kc) {
    int k0 = kc * 32;
    int kcol = k0 + sh * 16;  // 16 channels staged by this thread
    __syncthreads();
    {
      const uint4* gw = (const uint4*)&Wb[(size_t)sr * 256 + kcol];
      uint4 v0 = gw[0], v1 = gw[1];
      *(uint4*)&sW[sr][sh * 16] = v0;
      *(uint4*)&sW[sr][sh * 16 + 8] = v1;
      const uint4* gx = (const uint4*)&h1T[(size_t)(i0 + sr) * 256 + kcol];
      uint4 x0 = gx[0], x1 = gx[1];
      unsigned rr[8] = {x0.x, x0.y, x0.z, x0.w, x1.x, x1.y, x1.z, x1.w};
      unsigned ww[8];
#pragma unroll
      for (int e = 0; e < 8; ++e) {  // BN1+relu fused while staging
        int ch = kcol + 2 * e;
        float f0 = bf2f((unsigned short)(rr[e] & 0xFFFFu));
        float f1 = bf2f((unsigned short)(rr[e] >> 16));
        f0 = fmaxf(fmaf(A[ch], f0, C[ch]), 0.f);
        f1 = fmaxf(fmaf(A[ch + 1], f1, C[ch + 1]), 0.f);
        ww[e] = (unsigned)f2bf(f0) | ((unsigned)f2bf(f1) << 16);
      }
      uint4 y0 = {ww[0], ww[1], ww[2], ww[3]};
      uint4 y1 = {ww[4], ww[5], ww[6], ww[7]};
      *(uint4*)&sX[sr][sh * 16] = y0;
      *(uint4*)&sX[sr][sh * 16 + 8] = y1;
    }
    __syncthreads();
    bf16x8 a[4], b[4];
#pragma unroll
    for (int tm = 0; tm < 4; ++tm)
      a[tm] = *(const bf16x8*)&sW[wc + tm * 16 + l15][g * 8];
#pragma unroll
    for (int tn = 0; tn < 4; ++tn)
      b[tn] = *(const bf16x8*)&sX[wn + tn * 16 + l15][g * 8];
#pragma unroll
    for (int tm = 0; tm < 4; ++tm)
#pragma unroll
      for (int tn = 0; tn < 4; ++tn)
        acc[tm][tn] = __builtin_amdgcn_mfma_f32_16x16x32_bf16(a[tm], b[tn], acc[tm][tn], 0, 0, 0);
  }
#pragma unroll
  for (int tm = 0; tm < 4; ++tm)
#pragma unroll
    for (int tn = 0; tn < 4; ++tn) {
      int c = wc + tm * 16 + g * 4;
      int n = i0 + wn + tn * 16 + l15;
      f32x4 v = acc[tm][tn];
      *(float4*)&o2[(size_t)n * 128 + c] = make_float4(v[0], v[1], v[2], v[3]);
    }
}

// final: out2T [i][128] + BN2 + relu -> d_out [B][128][16384] (transposed)
__global__ __launch_bounds__(256) void final_k(const float* __restrict__ o2,
                                               const float* __restrict__ A,
                                               const float* __restrict__ C,
                                               float* __restrict__ out) {
  __shared__ float tile[32][33];
  int b = blockIdx.z;
  int n0 = blockIdx.x * 32;
  int c0 = blockIdx.y * 32;
  int tx = threadIdx.x, ty = threadIdx.y;
  float a = A[c0 + tx], cc = C[c0 + tx];
  for (int r = ty; r < 32; r += 8) {
    float v = o2[(size_t)(b * 16384 + n0 + r) * 128 + c0 + tx];
    tile[r][tx] = fmaxf(fmaf(a, v, cc), 0.f);
  }
  __syncthreads();
  for (int r = ty; r < 32; r += 8)
    out[((size_t)(b * 128 + c0 + r)) * 16384 + n0 + tx] = tile[tx][r];
}

extern "C" void kernel_launch(void* const* d_in, const int* in_sizes, int n_in,
                              void* d_out, int out_size, void* d_ws, size_t ws_size,
                              hipStream_t stream) {
  const float* xyz1 = (const float*)d_in[0];
  const float* xyz2 = (const float*)d_in[1];
  const float* p1   = (const float*)d_in[2];
  const float* p2   = (const float*)d_in[3];
  const int*   idx1 = (const int*)d_in[4];
  const int*   idx2 = (const int*)d_in[5];
  const float* w1   = (const float*)d_in[6];
  // d_in[7]=b1, d_in[11]=b2: exactly absorbed by BN mean subtraction
  const float* g1   = (const float*)d_in[8];
  const float* be1  = (const float*)d_in[9];
  const float* w2   = (const float*)d_in[10];
  const float* g2   = (const float*)d_in[12];
  const float* be2  = (const float*)d_in[13];
  float* out = (float*)d_out;

  char* ws = (char*)d_ws;
  int*            idx3 = (int*)(ws + 0x0);                      // 0.75MB
  float*          wgt  = (float*)(ws + 0xC0000);                // 0.75MB
  float*          rec  = (float*)(ws + 0x180000);               // 6MB
  unsigned short* X    = (unsigned short*)(ws + 0x780000);      // 48MB
  unsigned short* h1T  = (unsigned short*)(ws + 0x3780000);     // 32MB
  float*          p2t  = (float*)(ws + 0x3780000);              // alias h1T
  float*          o2   = (float*)(ws + 0x5780000);              // 32MB
  unsigned short* w1b  = (unsigned short*)(ws + 0x7780000);
  unsigned short* w2b  = (unsigned short*)(ws + 0x77B0000);
  float*          part1 = (float*)(ws + 0x77C0000);
  float*          part2 = (float*)(ws + 0x7840000);
  float*          a1   = (float*)(ws + 0x7880000);
  float*          c1   = a1 + 256;
  float*          a2   = c1 + 256;
  float*          c2   = a2 + 128;

  hipLaunchKernelGGL(transpose_k, dim3(128, 8, 4), dim3(32, 8), 0, stream, p2, p2t);
  hipLaunchKernelGGL(wcvt_k, dim3(512), dim3(256), 0, stream, w1, w2, w1b, w2b);
  hipLaunchKernelGGL(p1t_k, dim3(512, 4, 4), dim3(32, 8), 0, stream, p1, X);
  hipLaunchKernelGGL(knn_k, dim3(512), dim3(256), 0, stream,
                     xyz1, xyz2, idx1, idx2, rec);
  hipLaunchKernelGGL(knnmerge_k, dim3(256), dim3(256), 0, stream, rec, idx3, wgt);
  hipLaunchKernelGGL(interp_k, dim3(512), dim3(256), 0, stream, p2t, idx3, wgt, X);
  hipLaunchKernelGGL(gemm1_k, dim3(512, 2), dim3(256), 0, stream, X, w1b, h1T);
  hipLaunchKernelGGL(bnstats1_k, dim3(256), dim3(256), 0, stream, h1T, part1);
  hipLaunchKernelGGL((bnfold_k<256>), dim3(1), dim3(256), 0, stream, part1, g1, be1, a1, c1);
  hipLaunchKernelGGL(gemm2_k, dim3(512), dim3(256), 0, stream, h1T, w2b, a1, c1, o2);
  hipLaunchKernelGGL(bnstats2_k, dim3(256), dim3(256), 0, stream, o2, part2);
  hipLaunchKernelGGL((bnfold_k<128>), dim3(1), dim3(256), 0, stream, part2, g2, be2, a2, c2);
  hipLaunchKernelGGL(final_k, dim3(512, 4, 4), dim3(32, 8), 0, stream, o2, a2, c2, out);
}

// Round 8
// 283.340 us; speedup vs baseline: 1.0478x; 1.0478x over previous
//
#include <hip/hip_runtime.h>
#include <hip/hip_bf16.h>

#define INF_F (__builtin_inff())

typedef __attribute__((ext_vector_type(8))) short bf16x8;
typedef __attribute__((ext_vector_type(4))) float f32x4;

__device__ __forceinline__ unsigned short f2bf(float f) {
  __hip_bfloat16 h = __float2bfloat16(f);
  return __builtin_bit_cast(unsigned short, h);
}
__device__ __forceinline__ float bf2f(unsigned short u) {
  return __uint_as_float((unsigned)u << 16);
}

// ---------------------------------------------------------------------------
// B=4, N=16384, S=4096, D1=128, D2=256, MLP=(256,128). M = B*N = 65536.
// X: [65536][384] bf16 (cols 0..127 = points1^T, 128..383 = interp)
// h1T: [65536][256] bf16 ; out2T: [65536][128] fp32.
// GEMMs: D[c][n] = W[c][k] * X[n][k] via mfma_f32_16x16x32_bf16.
// ---------------------------------------------------------------------------

// points2 [B][256][4096] fp32 -> p2t [B][4096][256] bf16 (coalesced gather rows)
__global__ __launch_bounds__(256) void transpose_k(const float* __restrict__ in,
                                                   unsigned short* __restrict__ out) {
  __shared__ float tile[32][33];
  int b = blockIdx.z;
  int s0 = blockIdx.x * 32;
  int k0 = blockIdx.y * 32;
  int tx = threadIdx.x, ty = threadIdx.y;  // 32 x 8
  const float* src = in + ((size_t)b * 256 + k0) * 4096 + s0;
  for (int r = ty; r < 32; r += 8) tile[r][tx] = src[(size_t)r * 4096 + tx];
  __syncthreads();
  unsigned short* dst = out + ((size_t)b * 4096 + s0) * 256 + k0;
  for (int r = ty; r < 32; r += 8) dst[(size_t)r * 256 + tx] = f2bf(tile[tx][r]);
}

// p1 [B][128][16384] fp32 -> X[b*16384+n][0..127] bf16 (transposed)
__global__ __launch_bounds__(256) void p1t_k(const float* __restrict__ p1,
                                             unsigned short* __restrict__ X) {
  __shared__ float tile[32][33];
  int b = blockIdx.z;
  int n0 = blockIdx.x * 32;
  int c0 = blockIdx.y * 32;
  int tx = threadIdx.x, ty = threadIdx.y;
  const float* src = p1 + ((size_t)b * 128 + c0) * 16384 + n0;
  for (int r = ty; r < 32; r += 8) tile[r][tx] = src[(size_t)r * 16384 + tx];
  __syncthreads();
  for (int r = ty; r < 32; r += 8)
    X[((size_t)(b * 16384 + n0 + r)) * 384 + c0 + tx] = f2bf(tile[tx][r]);
}

// w1 [256][384], w2 [128][256] fp32 -> bf16 copies (same layout)
__global__ __launch_bounds__(256) void wcvt_k(const float* __restrict__ w1,
                                              const float* __restrict__ w2,
                                              unsigned short* __restrict__ w1b,
                                              unsigned short* __restrict__ w2b) {
  int id = blockIdx.x * 256 + threadIdx.x;
  if (id < 98304) w1b[id] = f2bf(w1[id]);
  else w2b[id - 98304] = f2bf(w2[id - 98304]);
}

// cold path: exact per-query rescan of one slice with this query's own id
__device__ __noinline__ void knn_fallback(const float* __restrict__ xyz2,
                                          const int* __restrict__ idx2,
                                          int b, int sbase, int myid,
                                          float px, float py, float pz, float pn,
                                          float& e0, float& e1, float& e2,
                                          int& j0, int& j1, int& j2) {
  e0 = e1 = e2 = INF_F; j0 = j1 = j2 = 0;
  for (int s = 0; s < 256; ++s) {
    int gs = sbase + s;
    float x = xyz2[(b * 3 + 0) * 4096 + gs];
    float y = xyz2[(b * 3 + 1) * 4096 + gs];
    float z = xyz2[(b * 3 + 2) * 4096 + gs];
    float w = fmaf(x, x, fmaf(y, y, z * z));
    float d = fmaf(-2.f, fmaf(px, x, fmaf(py, y, pz * z)), pn + w);
    d = (idx2[b * 4096 + gs] == myid) ? d : INF_F;
    if (d < e2) {
      bool l0 = d < e0, l1 = d < e1;
      e2 = l1 ? e1 : d; j2 = l1 ? j1 : gs;
      e1 = l0 ? e0 : (l1 ? d : e1); j1 = l0 ? j0 : (l1 ? gs : j1);
      e0 = l0 ? d : e0; j0 = l0 ? gs : j0;
    }
  }
}

// 3-NN stage 1. 1024 blocks = 64 query-chunks (1024 q) x 16 S-slices (256
// src, 4KB LDS). 256 thr x 4 queries/thread: one broadcast ds_read_b128
// feeds 256 pairs (R6/R7 bound: LDS-pipe ~12cyc/b128 + VALU issue).
// R7 lessons: keep 1024 blocks (grid halving cost 36us) and pin occupancy
// via __launch_bounds__(256,2) so the allocator keeps state in VGPRs.
// Validity folded into staged |p|^2 (3e38 if batch-id != common -> d>BIG ->
// weight 0). Branchy top-3 insert, strict < + ascending s = top_k ties.
// Per-query exact slow path if its id != common (never on this data).
__global__ __launch_bounds__(256, 2) void knn_k(const float* __restrict__ xyz1,
                                                const float* __restrict__ xyz2,
                                                const int* __restrict__ idx1,
                                                const int* __restrict__ idx2,
                                                float* __restrict__ rec) {
  __shared__ float4 sP[256];  // 4KB
  int bid = blockIdx.x;
  int chunk = bid >> 4, sl = bid & 15;
  int b = chunk >> 4;            // 16 chunks per batch (1024 queries each)
  int nloc = (chunk & 15) << 10; // query base within batch
  int t = threadIdx.x;
  int common = idx1[b * 16384 + nloc];
  int sbase = sl << 8;
  {
    int gs = sbase + t;
    float x = xyz2[(b * 3 + 0) * 4096 + gs];
    float y = xyz2[(b * 3 + 1) * 4096 + gs];
    float z = xyz2[(b * 3 + 2) * 4096 + gs];
    float w = fmaf(x, x, fmaf(y, y, z * z));
    int sid = idx2[b * 4096 + gs];
    w = (sid == common) ? w : 3e38f;
    sP[t] = make_float4(x, y, z, w);
  }
  __syncthreads();
  float px[4], py[4], pz[4], pn[4];
  float e0[4], e1[4], e2[4];
  int j0[4], j1[4], j2[4];
  int myid[4];
#pragma unroll
  for (int j = 0; j < 4; ++j) {
    int q = nloc + t + (j << 8);
    px[j] = xyz1[(b * 3 + 0) * 16384 + q];
    py[j] = xyz1[(b * 3 + 1) * 16384 + q];
    pz[j] = xyz1[(b * 3 + 2) * 16384 + q];
    myid[j] = idx1[b * 16384 + q];
    pn[j] = fmaf(px[j], px[j], fmaf(py[j], py[j], pz[j] * pz[j]));
    e0[j] = INF_F; e1[j] = INF_F; e2[j] = INF_F;
    j0[j] = 0; j1[j] = 0; j2[j] = 0;
  }
#pragma unroll 2
  for (int s = 0; s < 256; ++s) {
    float4 p = sP[s];  // wave-uniform addr -> LDS broadcast, conflict-free
    int sj = sbase + s;
#pragma unroll
    for (int j = 0; j < 4; ++j) {
      float d = fmaf(-2.f, fmaf(px[j], p.x, fmaf(py[j], p.y, pz[j] * p.z)),
                     pn[j] + p.w);  // ref formula |a|^2+|b|^2-2ab
      if (d < e2[j]) {  // rare past warmup
        bool l0 = d < e0[j], l1 = d < e1[j];
        e2[j] = l1 ? e1[j] : d;
        j2[j] = l1 ? j1[j] : sj;
        e1[j] = l0 ? e0[j] : (l1 ? d : e1[j]);
        j1[j] = l0 ? j0[j] : (l1 ? sj : j1[j]);
        e0[j] = l0 ? d : e0[j];
        j0[j] = l0 ? sj : j0[j];
      }
    }
  }
#pragma unroll
  for (int j = 0; j < 4; ++j) {
    if (__builtin_expect(myid[j] != common, 0))
      knn_fallback(xyz2, idx2, b, sbase, myid[j], px[j], py[j], pz[j], pn[j],
                   e0[j], e1[j], e2[j], j0[j], j1[j], j2[j]);
  }
#pragma unroll
  for (int j = 0; j < 4; ++j) {
    size_t q = (size_t)b * 16384 + nloc + t + (j << 8);
    float* r = &rec[(q * 16 + sl) * 6];
    r[0] = e0[j]; r[1] = e1[j]; r[2] = e2[j];
    ((int*)r)[3] = j0[j]; ((int*)r)[4] = j1[j]; ((int*)r)[5] = j2[j];
  }
}

// 3-NN stage 2: merge 16 S-slice records (ascending slice order, lex (d,idx)
// = exact top_k tie semantics), compute inverse-distance weights.
__global__ __launch_bounds__(256) void knnmerge_k(const float* __restrict__ rec,
                                                  int* __restrict__ idx3,
                                                  float* __restrict__ wgt) {
  int i = blockIdx.x * 256 + threadIdx.x;  // 65536 queries
  const float* rA = &rec[(size_t)i * 96];
  const int* iA = (const int*)rA;
  float e0 = rA[0], e1 = rA[1], e2 = rA[2];
  int j0 = iA[3], j1 = iA[4], j2 = iA[5];
  for (int c = 1; c < 16; ++c) {
#pragma unroll
    for (int w = 0; w < 3; ++w) {
      float d = rA[c * 6 + w];
      int sj = iA[c * 6 + 3 + w];
      bool l0 = (d < e0) || (d == e0 && sj < j0);
      bool l1 = (d < e1) || (d == e1 && sj < j1);
      bool l2 = (d < e2) || (d == e2 && sj < j2);
      e2 = l1 ? e1 : (l2 ? d : e2);
      j2 = l1 ? j1 : (l2 ? sj : j2);
      e1 = l0 ? e0 : (l1 ? d : e1);
      j1 = l0 ? j0 : (l1 ? sj : j1);
      e0 = l0 ? d : e0;
      j0 = l0 ? sj : j0;
    }
  }
  float r0 = 1.f / (e0 + 1e-8f);
  float r1 = 1.f / (e1 + 1e-8f);
  float r2 = 1.f / (e2 + 1e-8f);
  float rs = r0 + r1 + r2;
  float w0 = (e0 > 1e8f) ? 0.f : r0 / rs;  // ref: where(d3>BIG,0)+nan_to_num
  float w1 = (e1 > 1e8f) ? 0.f : r1 / rs;
  float w2 = (e2 > 1e8f) ? 0.f : r2 / rs;
  idx3[(size_t)i * 3 + 0] = j0; idx3[(size_t)i * 3 + 1] = j1; idx3[(size_t)i * 3 + 2] = j2;
  wgt[(size_t)i * 3 + 0] = w0;  wgt[(size_t)i * 3 + 1] = w1;  wgt[(size_t)i * 3 + 2] = w2;
}

// interp (bf16 p2t rows) -> X[i][128+k] bf16
__global__ __launch_bounds__(256) void interp_k(const unsigned short* __restrict__ p2t,
                                                const int* __restrict__ idx3,
                                                const float* __restrict__ wgt,
                                                unsigned short* __restrict__ X) {
  int i0 = blockIdx.x * 128;
  int b = i0 >> 14;
  int k = threadIdx.x;
  const unsigned short* base = p2t + (size_t)b * 4096 * 256;
#pragma unroll 2
  for (int ii = 0; ii < 128; ++ii) {
    int i = i0 + ii;
    int id0 = idx3[i * 3 + 0], id1 = idx3[i * 3 + 1], id2 = idx3[i * 3 + 2];
    float w0 = wgt[i * 3 + 0], w1v = wgt[i * 3 + 1], w2v = wgt[i * 3 + 2];
    float v = w0 * bf2f(base[id0 * 256 + k]);
    v = fmaf(w1v, bf2f(base[id1 * 256 + k]), v);
    v = fmaf(w2v, bf2f(base[id2 * 256 + k]), v);
    X[(size_t)i * 384 + 128 + k] = f2bf(v);
  }
}

// GEMM1 (MFMA): h1T[n][c] = sum_k w1[c][k] X[n][k]. 128x128 tile, BK=32,
// K=384. grid (512, 2).
__global__ __launch_bounds__(256) void gemm1_k(const unsigned short* __restrict__ X,
                                               const unsigned short* __restrict__ Wb,
                                               unsigned short* __restrict__ h1T) {
  __shared__ unsigned short sW[128][40];
  __shared__ unsigned short sX[128][40];
  int t = threadIdx.x;
  int i0 = blockIdx.x * 128;
  int c0 = blockIdx.y * 128;
  int w = t >> 6, lane = t & 63;
  int wc = (w & 1) * 64, wn = (w >> 1) * 64;
  int l15 = lane & 15, g = lane >> 4;
  f32x4 acc[4][4];
#pragma unroll
  for (int a = 0; a < 4; ++a)
#pragma unroll
    for (int bq = 0; bq < 4; ++bq) acc[a][bq] = (f32x4)0.f;
  int sr = t & 127, sh = t >> 7;
  for (int kc = 0; kc < 12; ++kc) {
    int k0 = kc * 32;
    __syncthreads();
    {
      const uint4* gw = (const uint4*)&Wb[(size_t)(c0 + sr) * 384 + k0 + sh * 16];
      uint4 v0 = gw[0], v1 = gw[1];
      *(uint4*)&sW[sr][sh * 16] = v0;
      *(uint4*)&sW[sr][sh * 16 + 8] = v1;
      const uint4* gx = (const uint4*)&X[(size_t)(i0 + sr) * 384 + k0 + sh * 16];
      uint4 x0 = gx[0], x1 = gx[1];
      *(uint4*)&sX[sr][sh * 16] = x0;
      *(uint4*)&sX[sr][sh * 16 + 8] = x1;
    }
    __syncthreads();
    bf16x8 a[4], b[4];
#pragma unroll
    for (int tm = 0; tm < 4; ++tm)
      a[tm] = *(const bf16x8*)&sW[wc + tm * 16 + l15][g * 8];
#pragma unroll
    for (int tn = 0; tn < 4; ++tn)
      b[tn] = *(const bf16x8*)&sX[wn + tn * 16 + l15][g * 8];
#pragma unroll
    for (int tm = 0; tm < 4; ++tm)
#pragma unroll
      for (int tn = 0; tn < 4; ++tn)
        acc[tm][tn] = __builtin_amdgcn_mfma_f32_16x16x32_bf16(a[tm], b[tn], acc[tm][tn], 0, 0, 0);
  }
#pragma unroll
  for (int tm = 0; tm < 4; ++tm)
#pragma unroll
    for (int tn = 0; tn < 4; ++tn) {
      int c = c0 + wc + tm * 16 + g * 4;
      int n = i0 + wn + tn * 16 + l15;
      f32x4 v = acc[tm][tn];
      ushort4 o;
      o.x = f2bf(v[0]); o.y = f2bf(v[1]); o.z = f2bf(v[2]); o.w = f2bf(v[3]);
      *(ushort4*)&h1T[(size_t)n * 256 + c] = o;
    }
}

// BN1 stats over h1T bf16 [65536][256]
__global__ __launch_bounds__(256) void bnstats1_k(const unsigned short* __restrict__ h,
                                                  float* __restrict__ part) {
  int t = threadIdx.x, q = t & 63, ro = t >> 6;
  int r0 = blockIdx.x * 256;
  float s0 = 0, s1 = 0, s2 = 0, s3 = 0, q0 = 0, q1 = 0, q2 = 0, q3 = 0;
  for (int it = 0; it < 64; ++it) {
    size_t r = r0 + it * 4 + ro;
    ushort4 v = *(const ushort4*)&h[r * 256 + q * 4];
    float f0 = bf2f(v.x), f1 = bf2f(v.y), f2 = bf2f(v.z), f3 = bf2f(v.w);
    s0 += f0; q0 += f0 * f0;
    s1 += f1; q1 += f1 * f1;
    s2 += f2; q2 += f2 * f2;
    s3 += f3; q3 += f3 * f3;
  }
  __shared__ float sm[256][8];
  sm[t][0] = s0; sm[t][1] = s1; sm[t][2] = s2; sm[t][3] = s3;
  sm[t][4] = q0; sm[t][5] = q1; sm[t][6] = q2; sm[t][7] = q3;
  __syncthreads();
  if (t < 64) {
#pragma unroll
    for (int j = 1; j < 4; ++j)
#pragma unroll
      for (int e = 0; e < 8; ++e) sm[t][e] += sm[t + 64 * j][e];
#pragma unroll
    for (int i = 0; i < 4; ++i) {
      part[((size_t)blockIdx.x * 256 + t * 4 + i) * 2 + 0] = sm[t][i];
      part[((size_t)blockIdx.x * 256 + t * 4 + i) * 2 + 1] = sm[t][4 + i];
    }
  }
}

// BN2 stats over out2T fp32 [65536][128]
__global__ __launch_bounds__(256) void bnstats2_k(const float* __restrict__ o2,
                                                  float* __restrict__ part) {
  int t = threadIdx.x, q = t & 31, ro = t >> 5;
  int r0 = blockIdx.x * 256;
  float s0 = 0, s1 = 0, s2 = 0, s3 = 0, q0 = 0, q1 = 0, q2 = 0, q3 = 0;
  for (int it = 0; it < 32; ++it) {
    size_t r = r0 + it * 8 + ro;
    float4 v = *(const float4*)&o2[r * 128 + q * 4];
    s0 += v.x; q0 += v.x * v.x;
    s1 += v.y; q1 += v.y * v.y;
    s2 += v.z; q2 += v.z * v.z;
    s3 += v.w; q3 += v.w * v.w;
  }
  __shared__ float sm[256][8];
  sm[t][0] = s0; sm[t][1] = s1; sm[t][2] = s2; sm[t][3] = s3;
  sm[t][4] = q0; sm[t][5] = q1; sm[t][6] = q2; sm[t][7] = q3;
  __syncthreads();
  if (t < 32) {
#pragma unroll
    for (int j = 1; j < 8; ++j)
#pragma unroll
      for (int e = 0; e < 8; ++e) sm[t][e] += sm[t + 32 * j][e];
#pragma unroll
    for (int i = 0; i < 4; ++i) {
      part[((size_t)blockIdx.x * 128 + t * 4 + i) * 2 + 0] = sm[t][i];
      part[((size_t)blockIdx.x * 128 + t * 4 + i) * 2 + 1] = sm[t][4 + i];
    }
  }
}

// fold partials -> per-channel a*x + c
template <int C>
__global__ __launch_bounds__(256) void bnfold_k(const float* __restrict__ part,
                                                const float* __restrict__ g,
                                                const float* __restrict__ be,
                                                float* __restrict__ A,
                                                float* __restrict__ Cc) {
  int c = threadIdx.x;
  if (c >= C) return;
  float s1 = 0.f, s2 = 0.f;
  for (int b = 0; b < 256; ++b) {
    s1 += part[((size_t)b * C + c) * 2 + 0];
    s2 += part[((size_t)b * C + c) * 2 + 1];
  }
  float mean = s1 * (1.f / 65536.f);
  float var = s2 * (1.f / 65536.f) - mean * mean;  // biased, as torch BN
  float a = g[c] * rsqrtf(var + 1e-5f);
  A[c] = a;
  Cc[c] = be[c] - mean * a;
}

// GEMM2 (MFMA) with fused BN1+ReLU on staging: out2T[n][c2] =
// sum_k w2[c2][k] relu(a1[k]*h1T[n][k]+c1[k]). K=256. grid (512).
__global__ __launch_bounds__(256) void gemm2_k(const unsigned short* __restrict__ h1T,
                                               const unsigned short* __restrict__ Wb,
                                               const float* __restrict__ A,
                                               const float* __restrict__ C,
                                               float* __restrict__ o2) {
  __shared__ unsigned short sW[128][40];
  __shared__ unsigned short sX[128][40];
  int t = threadIdx.x;
  int i0 = blockIdx.x * 128;
  int w = t >> 6, lane = t & 63;
  int wc = (w & 1) * 64, wn = (w >> 1) * 64;
  int l15 = lane & 15, g = lane >> 4;
  f32x4 acc[4][4];
#pragma unroll
  for (int a = 0; a < 4; ++a)
#pragma unroll
    for (int bq = 0; bq < 4; ++bq) acc[a][bq] = (f32x4)0.f;
  int sr = t & 127, sh = t >> 7;
  for (int kc = 0; kc < 8; ++kc) {
    int k0 = kc * 32;
    int kcol = k0 + sh * 16;
    __syncthreads();
    {
      const uint4* gw = (const uint4*)&Wb[(size_t)sr * 256 + kcol];
      uint4 v0 = gw[0], v1 = gw[1];
      *(uint4*)&sW[sr][sh * 16] = v0;
      *(uint4*)&sW[sr][sh * 16 + 8] = v1;
      const uint4* gx = (const uint4*)&h1T[(size_t)(i0 + sr) * 256 + kcol];
      uint4 x0 = gx[0], x1 = gx[1];
      unsigned rr[8] = {x0.x, x0.y, x0.z, x0.w, x1.x, x1.y, x1.z, x1.w};
      unsigned ww[8];
#pragma unroll
      for (int e = 0; e < 8; ++e) {  // BN1+relu fused while staging
        int ch = kcol + 2 * e;
        float f0 = bf2f((unsigned short)(rr[e] & 0xFFFFu));
        float f1 = bf2f((unsigned short)(rr[e] >> 16));
        f0 = fmaxf(fmaf(A[ch], f0, C[ch]), 0.f);
        f1 = fmaxf(fmaf(A[ch + 1], f1, C[ch + 1]), 0.f);
        ww[e] = (unsigned)f2bf(f0) | ((unsigned)f2bf(f1) << 16);
      }
      uint4 y0 = {ww[0], ww[1], ww[2], ww[3]};
      uint4 y1 = {ww[4], ww[5], ww[6], ww[7]};
      *(uint4*)&sX[sr][sh * 16] = y0;
      *(uint4*)&sX[sr][sh * 16 + 8] = y1;
    }
    __syncthreads();
    bf16x8 a[4], b[4];
#pragma unroll
    for (int tm = 0; tm < 4; ++tm)
      a[tm] = *(const bf16x8*)&sW[wc + tm * 16 + l15][g * 8];
#pragma unroll
    for (int tn = 0; tn < 4; ++tn)
      b[tn] = *(const bf16x8*)&sX[wn + tn * 16 + l15][g * 8];
#pragma unroll
    for (int tm = 0; tm < 4; ++tm)
#pragma unroll
      for (int tn = 0; tn < 4; ++tn)
        acc[tm][tn] = __builtin_amdgcn_mfma_f32_16x16x32_bf16(a[tm], b[tn], acc[tm][tn], 0, 0, 0);
  }
#pragma unroll
  for (int tm = 0; tm < 4; ++tm)
#pragma unroll
    for (int tn = 0; tn < 4; ++tn) {
      int c = wc + tm * 16 + g * 4;
      int n = i0 + wn + tn * 16 + l15;
      f32x4 v = acc[tm][tn];
      *(float4*)&o2[(size_t)n * 128 + c] = make_float4(v[0], v[1], v[2], v[3]);
    }
}

// final: out2T [i][128] + BN2 + relu -> d_out [B][128][16384] (transposed)
__global__ __launch_bounds__(256) void final_k(const float* __restrict__ o2,
                                               const float* __restrict__ A,
                                               const float* __restrict__ C,
                                               float* __restrict__ out) {
  __shared__ float tile[32][33];
  int b = blockIdx.z;
  int n0 = blockIdx.x * 32;
  int c0 = blockIdx.y * 32;
  int tx = threadIdx.x, ty = threadIdx.y;
  float a = A[c0 + tx], cc = C[c0 + tx];
  for (int r = ty; r < 32; r += 8) {
    float v = o2[(size_t)(b * 16384 + n0 + r) * 128 + c0 + tx];
    tile[r][tx] = fmaxf(fmaf(a, v, cc), 0.f);
  }
  __syncthreads();
  for (int r = ty; r < 32; r += 8)
    out[((size_t)(b * 128 + c0 + r)) * 16384 + n0 + tx] = tile[tx][r];
}

extern "C" void kernel_launch(void* const* d_in, const int* in_sizes, int n_in,
                              void* d_out, int out_size, void* d_ws, size_t ws_size,
                              hipStream_t stream) {
  const float* xyz1 = (const float*)d_in[0];
  const float* xyz2 = (const float*)d_in[1];
  const float* p1   = (const float*)d_in[2];
  const float* p2   = (const float*)d_in[3];
  const int*   idx1 = (const int*)d_in[4];
  const int*   idx2 = (const int*)d_in[5];
  const float* w1   = (const float*)d_in[6];
  // d_in[7]=b1, d_in[11]=b2: exactly absorbed by BN mean subtraction
  const float* g1   = (const float*)d_in[8];
  const float* be1  = (const float*)d_in[9];
  const float* w2   = (const float*)d_in[10];
  const float* g2   = (const float*)d_in[12];
  const float* be2  = (const float*)d_in[13];
  float* out = (float*)d_out;

  char* ws = (char*)d_ws;
  // idx3 | wgt | X 48MB | h1T 32MB (p2t bf16 8.4MB aliased, dead before
  // gemm1 writes) | o2 32MB (rec 25.2MB aliased, dead before gemm2 writes)
  // | w1b w2b part1 part2 params  => ~114MB
  int*            idx3 = (int*)(ws + 0x0);                      // 0.75MB
  float*          wgt  = (float*)(ws + 0xC0000);                // 0.75MB
  unsigned short* X    = (unsigned short*)(ws + 0x180000);      // 48MB
  unsigned short* h1T  = (unsigned short*)(ws + 0x3180000);     // 32MB
  unsigned short* p2t  = (unsigned short*)(ws + 0x3180000);     // alias h1T
  float*          o2   = (float*)(ws + 0x5180000);              // 32MB
  float*          rec  = (float*)(ws + 0x5180000);              // alias o2
  unsigned short* w1b  = (unsigned short*)(ws + 0x7180000);
  unsigned short* w2b  = (unsigned short*)(ws + 0x71B0000);
  float*          part1 = (float*)(ws + 0x71C0000);
  float*          part2 = (float*)(ws + 0x7240000);
  float*          a1   = (float*)(ws + 0x7280000);
  float*          c1   = a1 + 256;
  float*          a2   = c1 + 256;
  float*          c2   = a2 + 128;

  hipLaunchKernelGGL(transpose_k, dim3(128, 8, 4), dim3(32, 8), 0, stream, p2, p2t);
  hipLaunchKernelGGL(wcvt_k, dim3(512), dim3(256), 0, stream, w1, w2, w1b, w2b);
  hipLaunchKernelGGL(p1t_k, dim3(512, 4, 4), dim3(32, 8), 0, stream, p1, X);
  hipLaunchKernelGGL(knn_k, dim3(1024), dim3(256), 0, stream,
                     xyz1, xyz2, idx1, idx2, rec);
  hipLaunchKernelGGL(knnmerge_k, dim3(256), dim3(256), 0, stream, rec, idx3, wgt);
  hipLaunchKernelGGL(interp_k, dim3(512), dim3(256), 0, stream, p2t, idx3, wgt, X);
  hipLaunchKernelGGL(gemm1_k, dim3(512, 2), dim3(256), 0, stream, X, w1b, h1T);
  hipLaunchKernelGGL(bnstats1_k, dim3(256), dim3(256), 0, stream, h1T, part1);
  hipLaunchKernelGGL((bnfold_k<256>), dim3(1), dim3(256), 0, stream, part1, g1, be1, a1, c1);
  hipLaunchKernelGGL(gemm2_k, dim3(512), dim3(256), 0, stream, h1T, w2b, a1, c1, o2);
  hipLaunchKernelGGL(bnstats2_k, dim3(256), dim3(256), 0, stream, o2, part2);
  hipLaunchKernelGGL((bnfold_k<128>), dim3(1), dim3(256), 0, stream, part2, g2, be2, a2, c2);
  hipLaunchKernelGGL(final_k, dim3(512, 4, 4), dim3(32, 8), 0, stream, o2, a2, c2, out);
}

// Round 9
// 274.196 us; speedup vs baseline: 1.0827x; 1.0333x over previous
//
#include <hip/hip_runtime.h>
#include <hip/hip_bf16.h>

#define INF_F (__builtin_inff())

typedef __attribute__((ext_vector_type(8))) short bf16x8;
typedef __attribute__((ext_vector_type(4))) float f32x4;

__device__ __forceinline__ unsigned short f2bf(float f) {
  __hip_bfloat16 h = __float2bfloat16(f);
  return __builtin_bit_cast(unsigned short, h);
}
__device__ __forceinline__ float bf2f(unsigned short u) {
  return __uint_as_float((unsigned)u << 16);
}

// branchless sorted top-3 insert on scalar state (macro => never address-taken)
#define TOP3_INS(d, sj, E0, E1, E2, J0, J1, J2)                      \
  {                                                                  \
    bool l0 = (d) < E0, l1 = (d) < E1;                               \
    E2 = l1 ? E1 : (d); J2 = l1 ? J1 : (sj);                         \
    E1 = l0 ? E0 : (l1 ? (d) : E1); J1 = l0 ? J0 : (l1 ? (sj) : J1); \
    E0 = l0 ? (d) : E0; J0 = l0 ? (sj) : J0;                         \
  }

// ---------------------------------------------------------------------------
// B=4, N=16384, S=4096, D1=128, D2=256, MLP=(256,128). M = B*N = 65536.
// X: [65536][384] bf16 (cols 0..127 = points1^T, 128..383 = interp)
// h1T: [65536][256] bf16 ; out2T: [65536][128] fp32.
// GEMMs: D[c][n] = W[c][k] * X[n][k] via mfma_f32_16x16x32_bf16.
// ---------------------------------------------------------------------------

// points2 [B][256][4096] fp32 -> p2t [B][4096][256] bf16 (coalesced gather rows)
__global__ __launch_bounds__(256) void transpose_k(const float* __restrict__ in,
                                                   unsigned short* __restrict__ out) {
  __shared__ float tile[32][33];
  int b = blockIdx.z;
  int s0 = blockIdx.x * 32;
  int k0 = blockIdx.y * 32;
  int tx = threadIdx.x, ty = threadIdx.y;  // 32 x 8
  const float* src = in + ((size_t)b * 256 + k0) * 4096 + s0;
  for (int r = ty; r < 32; r += 8) tile[r][tx] = src[(size_t)r * 4096 + tx];
  __syncthreads();
  unsigned short* dst = out + ((size_t)b * 4096 + s0) * 256 + k0;
  for (int r = ty; r < 32; r += 8) dst[(size_t)r * 256 + tx] = f2bf(tile[tx][r]);
}

// p1 [B][128][16384] fp32 -> X[b*16384+n][0..127] bf16 (transposed)
__global__ __launch_bounds__(256) void p1t_k(const float* __restrict__ p1,
                                             unsigned short* __restrict__ X) {
  __shared__ float tile[32][33];
  int b = blockIdx.z;
  int n0 = blockIdx.x * 32;
  int c0 = blockIdx.y * 32;
  int tx = threadIdx.x, ty = threadIdx.y;
  const float* src = p1 + ((size_t)b * 128 + c0) * 16384 + n0;
  for (int r = ty; r < 32; r += 8) tile[r][tx] = src[(size_t)r * 16384 + tx];
  __syncthreads();
  for (int r = ty; r < 32; r += 8)
    X[((size_t)(b * 16384 + n0 + r)) * 384 + c0 + tx] = f2bf(tile[tx][r]);
}

// w1 [256][384], w2 [128][256] fp32 -> bf16 copies (same layout)
__global__ __launch_bounds__(256) void wcvt_k(const float* __restrict__ w1,
                                              const float* __restrict__ w2,
                                              unsigned short* __restrict__ w1b,
                                              unsigned short* __restrict__ w2b) {
  int id = blockIdx.x * 256 + threadIdx.x;
  if (id < 98304) w1b[id] = f2bf(w1[id]);
  else w2b[id - 98304] = f2bf(w2[id - 98304]);
}

// 3-NN stage 1. 1024 blocks = 64 query-chunks (1024 q) x 16 S-slices (256
// src, 4KB LDS). 256 thr x 4 queries/thread: one broadcast ds_read_b128
// feeds 256 pairs. R8 lesson: NO address-taken state - the __noinline__
// fallback taking float& forced the top-3 arrays to scratch (VGPR 32,
// WRITE_SIZE 98MB). All state is named scalars + macros now.
// Validity folded into staged |p|^2 (3e38 if batch-id != common -> d>BIG ->
// weight 0). Strict < + ascending s = top_k tie order. Per-query exact
// inline fallback if its id != common (never taken on this data).
__global__ __launch_bounds__(256) void knn_k(const float* __restrict__ xyz1,
                                             const float* __restrict__ xyz2,
                                             const int* __restrict__ idx1,
                                             const int* __restrict__ idx2,
                                             float* __restrict__ rec) {
  __shared__ float4 sP[256];  // 4KB
  int bid = blockIdx.x;
  int chunk = bid >> 4, sl = bid & 15;
  int b = chunk >> 4;            // 16 chunks per batch (1024 queries each)
  int nloc = (chunk & 15) << 10; // query base within batch
  int t = threadIdx.x;
  int common = idx1[b * 16384 + nloc];
  int sbase = sl << 8;
  {
    int gs = sbase + t;
    float x = xyz2[(b * 3 + 0) * 4096 + gs];
    float y = xyz2[(b * 3 + 1) * 4096 + gs];
    float z = xyz2[(b * 3 + 2) * 4096 + gs];
    float w = fmaf(x, x, fmaf(y, y, z * z));
    int sid = idx2[b * 4096 + gs];
    w = (sid == common) ? w : 3e38f;
    sP[t] = make_float4(x, y, z, w);
  }
  __syncthreads();
  int q0i = b * 16384 + nloc + t;  // queries: q0i, +256, +512, +768
  float px0 = xyz1[(b * 3 + 0) * 16384 + nloc + t];
  float py0 = xyz1[(b * 3 + 1) * 16384 + nloc + t];
  float pz0 = xyz1[(b * 3 + 2) * 16384 + nloc + t];
  float px1 = xyz1[(b * 3 + 0) * 16384 + nloc + t + 256];
  float py1 = xyz1[(b * 3 + 1) * 16384 + nloc + t + 256];
  float pz1 = xyz1[(b * 3 + 2) * 16384 + nloc + t + 256];
  float px2 = xyz1[(b * 3 + 0) * 16384 + nloc + t + 512];
  float py2 = xyz1[(b * 3 + 1) * 16384 + nloc + t + 512];
  float pz2 = xyz1[(b * 3 + 2) * 16384 + nloc + t + 512];
  float px3 = xyz1[(b * 3 + 0) * 16384 + nloc + t + 768];
  float py3 = xyz1[(b * 3 + 1) * 16384 + nloc + t + 768];
  float pz3 = xyz1[(b * 3 + 2) * 16384 + nloc + t + 768];
  int id0 = idx1[q0i], id1 = idx1[q0i + 256], id2 = idx1[q0i + 512], id3 = idx1[q0i + 768];
  float pn0 = fmaf(px0, px0, fmaf(py0, py0, pz0 * pz0));
  float pn1 = fmaf(px1, px1, fmaf(py1, py1, pz1 * pz1));
  float pn2 = fmaf(px2, px2, fmaf(py2, py2, pz2 * pz2));
  float pn3 = fmaf(px3, px3, fmaf(py3, py3, pz3 * pz3));
  float e00 = INF_F, e10 = INF_F, e20 = INF_F;
  float e01 = INF_F, e11 = INF_F, e21 = INF_F;
  float e02 = INF_F, e12 = INF_F, e22 = INF_F;
  float e03 = INF_F, e13 = INF_F, e23 = INF_F;
  int j00 = 0, j10 = 0, j20 = 0;
  int j01 = 0, j11 = 0, j21 = 0;
  int j02 = 0, j12 = 0, j22 = 0;
  int j03 = 0, j13 = 0, j23 = 0;
#pragma unroll 2
  for (int s = 0; s < 256; ++s) {
    float4 p = sP[s];  // wave-uniform addr -> LDS broadcast, conflict-free
    int sj = sbase + s;
    float d0 = fmaf(-2.f, fmaf(px0, p.x, fmaf(py0, p.y, pz0 * p.z)), pn0 + p.w);
    float d1 = fmaf(-2.f, fmaf(px1, p.x, fmaf(py1, p.y, pz1 * p.z)), pn1 + p.w);
    float d2 = fmaf(-2.f, fmaf(px2, p.x, fmaf(py2, p.y, pz2 * p.z)), pn2 + p.w);
    float d3 = fmaf(-2.f, fmaf(px3, p.x, fmaf(py3, p.y, pz3 * p.z)), pn3 + p.w);
    if (d0 < e20) TOP3_INS(d0, sj, e00, e10, e20, j00, j10, j20);
    if (d1 < e21) TOP3_INS(d1, sj, e01, e11, e21, j01, j11, j21);
    if (d2 < e22) TOP3_INS(d2, sj, e02, e12, e22, j02, j12, j22);
    if (d3 < e23) TOP3_INS(d3, sj, e03, e13, e23, j03, j13, j23);
  }
  // exact inline fallback per query when its id != common (never on this data)
#define KNN_FB(MYID, PX, PY, PZ, PN, E0, E1, E2, J0, J1, J2)              \
  if (__builtin_expect((MYID) != common, 0)) {                            \
    E0 = INF_F; E1 = INF_F; E2 = INF_F; J0 = 0; J1 = 0; J2 = 0;           \
    for (int s = 0; s < 256; ++s) {                                       \
      int gs = sbase + s;                                                 \
      float x = xyz2[(b * 3 + 0) * 4096 + gs];                            \
      float y = xyz2[(b * 3 + 1) * 4096 + gs];                            \
      float z = xyz2[(b * 3 + 2) * 4096 + gs];                            \
      float w = fmaf(x, x, fmaf(y, y, z * z));                            \
      float d = fmaf(-2.f, fmaf(PX, x, fmaf(PY, y, (PZ) * z)), (PN) + w); \
      d = (idx2[b * 4096 + gs] == (MYID)) ? d : INF_F;                    \
      if (d < E2) TOP3_INS(d, gs, E0, E1, E2, J0, J1, J2);                \
    }                                                                     \
  }
  KNN_FB(id0, px0, py0, pz0, pn0, e00, e10, e20, j00, j10, j20);
  KNN_FB(id1, px1, py1, pz1, pn1, e01, e11, e21, j01, j11, j21);
  KNN_FB(id2, px2, py2, pz2, pn2, e02, e12, e22, j02, j12, j22);
  KNN_FB(id3, px3, py3, pz3, pn3, e03, e13, e23, j03, j13, j23);
#undef KNN_FB
  // rec layout [slice][query]: lane-consecutive 24B records => coalesced
  {
    float* r = &rec[((size_t)sl * 65536 + q0i) * 6];
    r[0] = e00; r[1] = e10; r[2] = e20;
    ((int*)r)[3] = j00; ((int*)r)[4] = j10; ((int*)r)[5] = j20;
    r = &rec[((size_t)sl * 65536 + q0i + 256) * 6];
    r[0] = e01; r[1] = e11; r[2] = e21;
    ((int*)r)[3] = j01; ((int*)r)[4] = j11; ((int*)r)[5] = j21;
    r = &rec[((size_t)sl * 65536 + q0i + 512) * 6];
    r[0] = e02; r[1] = e12; r[2] = e22;
    ((int*)r)[3] = j02; ((int*)r)[4] = j12; ((int*)r)[5] = j22;
    r = &rec[((size_t)sl * 65536 + q0i + 768) * 6];
    r[0] = e03; r[1] = e13; r[2] = e23;
    ((int*)r)[3] = j03; ((int*)r)[4] = j13; ((int*)r)[5] = j23;
  }
}

// 3-NN stage 2: merge 16 S-slice records (ascending slice order, lex (d,idx)
// = exact top_k tie semantics), compute inverse-distance weights.
__global__ __launch_bounds__(256) void knnmerge_k(const float* __restrict__ rec,
                                                  int* __restrict__ idx3,
                                                  float* __restrict__ wgt) {
  int i = blockIdx.x * 256 + threadIdx.x;  // 65536 queries
  float e0, e1, e2;
  int j0, j1, j2;
  {
    const float* r = &rec[(size_t)i * 6];
    e0 = r[0]; e1 = r[1]; e2 = r[2];
    j0 = ((const int*)r)[3]; j1 = ((const int*)r)[4]; j2 = ((const int*)r)[5];
  }
  for (int c = 1; c < 16; ++c) {
    const float* r = &rec[((size_t)c * 65536 + i) * 6];
    const int* ir = (const int*)r;
#pragma unroll
    for (int w = 0; w < 3; ++w) {
      float d = r[w];
      int sj = ir[3 + w];
      bool l0 = (d < e0) || (d == e0 && sj < j0);
      bool l1 = (d < e1) || (d == e1 && sj < j1);
      bool l2 = (d < e2) || (d == e2 && sj < j2);
      e2 = l1 ? e1 : (l2 ? d : e2);
      j2 = l1 ? j1 : (l2 ? sj : j2);
      e1 = l0 ? e0 : (l1 ? d : e1);
      j1 = l0 ? j0 : (l1 ? sj : j1);
      e0 = l0 ? d : e0;
      j0 = l0 ? sj : j0;
    }
  }
  float r0 = 1.f / (e0 + 1e-8f);
  float r1 = 1.f / (e1 + 1e-8f);
  float r2 = 1.f / (e2 + 1e-8f);
  float rs = r0 + r1 + r2;
  float w0 = (e0 > 1e8f) ? 0.f : r0 / rs;  // ref: where(d3>BIG,0)+nan_to_num
  float w1 = (e1 > 1e8f) ? 0.f : r1 / rs;
  float w2 = (e2 > 1e8f) ? 0.f : r2 / rs;
  idx3[(size_t)i * 3 + 0] = j0; idx3[(size_t)i * 3 + 1] = j1; idx3[(size_t)i * 3 + 2] = j2;
  wgt[(size_t)i * 3 + 0] = w0;  wgt[(size_t)i * 3 + 1] = w1;  wgt[(size_t)i * 3 + 2] = w2;
}

// interp (bf16 p2t rows) -> X[i][128+k] bf16
__global__ __launch_bounds__(256) void interp_k(const unsigned short* __restrict__ p2t,
                                                const int* __restrict__ idx3,
                                                const float* __restrict__ wgt,
                                                unsigned short* __restrict__ X) {
  int i0 = blockIdx.x * 128;
  int b = i0 >> 14;
  int k = threadIdx.x;
  const unsigned short* base = p2t + (size_t)b * 4096 * 256;
#pragma unroll 2
  for (int ii = 0; ii < 128; ++ii) {
    int i = i0 + ii;
    int id0 = idx3[i * 3 + 0], id1 = idx3[i * 3 + 1], id2 = idx3[i * 3 + 2];
    float w0 = wgt[i * 3 + 0], w1v = wgt[i * 3 + 1], w2v = wgt[i * 3 + 2];
    float v = w0 * bf2f(base[id0 * 256 + k]);
    v = fmaf(w1v, bf2f(base[id1 * 256 + k]), v);
    v = fmaf(w2v, bf2f(base[id2 * 256 + k]), v);
    X[(size_t)i * 384 + 128 + k] = f2bf(v);
  }
}

// GEMM1 (MFMA): h1T[n][c] = sum_k w1[c][k] X[n][k]. 128x128 tile, BK=32,
// K=384. grid (512, 2).
__global__ __launch_bounds__(256) void gemm1_k(const unsigned short* __restrict__ X,
                                               const unsigned short* __restrict__ Wb,
                                               unsigned short* __restrict__ h1T) {
  __shared__ unsigned short sW[128][40];
  __shared__ unsigned short sX[128][40];
  int t = threadIdx.x;
  int i0 = blockIdx.x * 128;
  int c0 = blockIdx.y * 128;
  int w = t >> 6, lane = t & 63;
  int wc = (w & 1) * 64, wn = (w >> 1) * 64;
  int l15 = lane & 15, g = lane >> 4;
  f32x4 acc[4][4];
#pragma unroll
  for (int a = 0; a < 4; ++a)
#pragma unroll
    for (int bq = 0; bq < 4; ++bq) acc[a][bq] = (f32x4)0.f;
  int sr = t & 127, sh = t >> 7;
  for (int kc = 0; kc < 12; ++kc) {
    int k0 = kc * 32;
    __syncthreads();
    {
      const uint4* gw = (const uint4*)&Wb[(size_t)(c0 + sr) * 384 + k0 + sh * 16];
      uint4 v0 = gw[0], v1 = gw[1];
      *(uint4*)&sW[sr][sh * 16] = v0;
      *(uint4*)&sW[sr][sh * 16 + 8] = v1;
      const uint4* gx = (const uint4*)&X[(size_t)(i0 + sr) * 384 + k0 + sh * 16];
      uint4 x0 = gx[0], x1 = gx[1];
      *(uint4*)&sX[sr][sh * 16] = x0;
      *(uint4*)&sX[sr][sh * 16 + 8] = x1;
    }
    __syncthreads();
    bf16x8 a[4], b[4];
#pragma unroll
    for (int tm = 0; tm < 4; ++tm)
      a[tm] = *(const bf16x8*)&sW[wc + tm * 16 + l15][g * 8];
#pragma unroll
    for (int tn = 0; tn < 4; ++tn)
      b[tn] = *(const bf16x8*)&sX[wn + tn * 16 + l15][g * 8];
#pragma unroll
    for (int tm = 0; tm < 4; ++tm)
#pragma unroll
      for (int tn = 0; tn < 4; ++tn)
        acc[tm][tn] = __builtin_amdgcn_mfma_f32_16x16x32_bf16(a[tm], b[tn], acc[tm][tn], 0, 0, 0);
  }
#pragma unroll
  for (int tm = 0; tm < 4; ++tm)
#pragma unroll
    for (int tn = 0; tn < 4; ++tn) {
      int c = c0 + wc + tm * 16 + g * 4;
      int n = i0 + wn + tn * 16 + l15;
      f32x4 v = acc[tm][tn];
      ushort4 o;
      o.x = f2bf(v[0]); o.y = f2bf(v[1]); o.z = f2bf(v[2]); o.w = f2bf(v[3]);
      *(ushort4*)&h1T[(size_t)n * 256 + c] = o;
    }
}

// BN1 stats over h1T bf16 [65536][256]
__global__ __launch_bounds__(256) void bnstats1_k(const unsigned short* __restrict__ h,
                                                  float* __restrict__ part) {
  int t = threadIdx.x, q = t & 63, ro = t >> 6;
  int r0 = blockIdx.x * 256;
  float s0 = 0, s1 = 0, s2 = 0, s3 = 0, q0 = 0, q1 = 0, q2 = 0, q3 = 0;
  for (int it = 0; it < 64; ++it) {
    size_t r = r0 + it * 4 + ro;
    ushort4 v = *(const ushort4*)&h[r * 256 + q * 4];
    float f0 = bf2f(v.x), f1 = bf2f(v.y), f2 = bf2f(v.z), f3 = bf2f(v.w);
    s0 += f0; q0 += f0 * f0;
    s1 += f1; q1 += f1 * f1;
    s2 += f2; q2 += f2 * f2;
    s3 += f3; q3 += f3 * f3;
  }
  __shared__ float sm[256][8];
  sm[t][0] = s0; sm[t][1] = s1; sm[t][2] = s2; sm[t][3] = s3;
  sm[t][4] = q0; sm[t][5] = q1; sm[t][6] = q2; sm[t][7] = q3;
  __syncthreads();
  if (t < 64) {
#pragma unroll
    for (int j = 1; j < 4; ++j)
#pragma unroll
      for (int e = 0; e < 8; ++e) sm[t][e] += sm[t + 64 * j][e];
#pragma unroll
    for (int i = 0; i < 4; ++i) {
      part[((size_t)blockIdx.x * 256 + t * 4 + i) * 2 + 0] = sm[t][i];
      part[((size_t)blockIdx.x * 256 + t * 4 + i) * 2 + 1] = sm[t][4 + i];
    }
  }
}

// BN2 stats over out2T fp32 [65536][128]
__global__ __launch_bounds__(256) void bnstats2_k(const float* __restrict__ o2,
                                                  float* __restrict__ part) {
  int t = threadIdx.x, q = t & 31, ro = t >> 5;
  int r0 = blockIdx.x * 256;
  float s0 = 0, s1 = 0, s2 = 0, s3 = 0, q0 = 0, q1 = 0, q2 = 0, q3 = 0;
  for (int it = 0; it < 32; ++it) {
    size_t r = r0 + it * 8 + ro;
    float4 v = *(const float4*)&o2[r * 128 + q * 4];
    s0 += v.x; q0 += v.x * v.x;
    s1 += v.y; q1 += v.y * v.y;
    s2 += v.z; q2 += v.z * v.z;
    s3 += v.w; q3 += v.w * v.w;
  }
  __shared__ float sm[256][8];
  sm[t][0] = s0; sm[t][1] = s1; sm[t][2] = s2; sm[t][3] = s3;
  sm[t][4] = q0; sm[t][5] = q1; sm[t][6] = q2; sm[t][7] = q3;
  __syncthreads();
  if (t < 32) {
#pragma unroll
    for (int j = 1; j < 8; ++j)
#pragma unroll
      for (int e = 0; e < 8; ++e) sm[t][e] += sm[t + 32 * j][e];
#pragma unroll
    for (int i = 0; i < 4; ++i) {
      part[((size_t)blockIdx.x * 128 + t * 4 + i) * 2 + 0] = sm[t][i];
      part[((size_t)blockIdx.x * 128 + t * 4 + i) * 2 + 1] = sm[t][4 + i];
    }
  }
}

// fold partials -> per-channel a*x + c
template <int C>
__global__ __launch_bounds__(256) void bnfold_k(const float* __restrict__ part,
                                                const float* __restrict__ g,
                                                const float* __restrict__ be,
                                                float* __restrict__ A,
                                                float* __restrict__ Cc) {
  int c = threadIdx.x;
  if (c >= C) return;
  float s1 = 0.f, s2 = 0.f;
  for (int b = 0; b < 256; ++b) {
    s1 += part[((size_t)b * C + c) * 2 + 0];
    s2 += part[((size_t)b * C + c) * 2 + 1];
  }
  float mean = s1 * (1.f / 65536.f);
  float var = s2 * (1.f / 65536.f) - mean * mean;  // biased, as torch BN
  float a = g[c] * rsqrtf(var + 1e-5f);
  A[c] = a;
  Cc[c] = be[c] - mean * a;
}

// GEMM2 (MFMA) with fused BN1+ReLU on staging: out2T[n][c2] =
// sum_k w2[c2][k] relu(a1[k]*h1T[n][k]+c1[k]). K=256. grid (512).
__global__ __launch_bounds__(256) void gemm2_k(const unsigned short* __restrict__ h1T,
                                               const unsigned short* __restrict__ Wb,
                                               const float* __restrict__ A,
                                               const float* __restrict__ C,
                                               float* __restrict__ o2) {
  __shared__ unsigned short sW[128][40];
  __shared__ unsigned short sX[128][40];
  int t = threadIdx.x;
  int i0 = blockIdx.x * 128;
  int w = t >> 6, lane = t & 63;
  int wc = (w & 1) * 64, wn = (w >> 1) * 64;
  int l15 = lane & 15, g = lane >> 4;
  f32x4 acc[4][4];
#pragma unroll
  for (int a = 0; a < 4; ++a)
#pragma unroll
    for (int bq = 0; bq < 4; ++bq) acc[a][bq] = (f32x4)0.f;
  int sr = t & 127, sh = t >> 7;
  for (int kc = 0; kc < 8; ++kc) {
    int k0 = kc * 32;
    int kcol = k0 + sh * 16;
    __syncthreads();
    {
      const uint4* gw = (const uint4*)&Wb[(size_t)sr * 256 + kcol];
      uint4 v0 = gw[0], v1 = gw[1];
      *(uint4*)&sW[sr][sh * 16] = v0;
      *(uint4*)&sW[sr][sh * 16 + 8] = v1;
      const uint4* gx = (const uint4*)&h1T[(size_t)(i0 + sr) * 256 + kcol];
      uint4 x0 = gx[0], x1 = gx[1];
      unsigned rr[8] = {x0.x, x0.y, x0.z, x0.w, x1.x, x1.y, x1.z, x1.w};
      unsigned ww[8];
#pragma unroll
      for (int e = 0; e < 8; ++e) {  // BN1+relu fused while staging
        int ch = kcol + 2 * e;
        float f0 = bf2f((unsigned short)(rr[e] & 0xFFFFu));
        float f1 = bf2f((unsigned short)(rr[e] >> 16));
        f0 = fmaxf(fmaf(A[ch], f0, C[ch]), 0.f);
        f1 = fmaxf(fmaf(A[ch + 1], f1, C[ch + 1]), 0.f);
        ww[e] = (unsigned)f2bf(f0) | ((unsigned)f2bf(f1) << 16);
      }
      uint4 y0 = {ww[0], ww[1], ww[2], ww[3]};
      uint4 y1 = {ww[4], ww[5], ww[6], ww[7]};
      *(uint4*)&sX[sr][sh * 16] = y0;
      *(uint4*)&sX[sr][sh * 16 + 8] = y1;
    }
    __syncthreads();
    bf16x8 a[4], b[4];
#pragma unroll
    for (int tm = 0; tm < 4; ++tm)
      a[tm] = *(const bf16x8*)&sW[wc + tm * 16 + l15][g * 8];
#pragma unroll
    for (int tn = 0; tn < 4; ++tn)
      b[tn] = *(const bf16x8*)&sX[wn + tn * 16 + l15][g * 8];
#pragma unroll
    for (int tm = 0; tm < 4; ++tm)
#pragma unroll
      for (int tn = 0; tn < 4; ++tn)
        acc[tm][tn] = __builtin_amdgcn_mfma_f32_16x16x32_bf16(a[tm], b[tn], acc[tm][tn], 0, 0, 0);
  }
#pragma unroll
  for (int tm = 0; tm < 4; ++tm)
#pragma unroll
    for (int tn = 0; tn < 4; ++tn) {
      int c = wc + tm * 16 + g * 4;
      int n = i0 + wn + tn * 16 + l15;
      f32x4 v = acc[tm][tn];
      *(float4*)&o2[(size_t)n * 128 + c] = make_float4(v[0], v[1], v[2], v[3]);
    }
}

// final: out2T [i][128] + BN2 + relu -> d_out [B][128][16384] (transposed)
__global__ __launch_bounds__(256) void final_k(const float* __restrict__ o2,
                                               const float* __restrict__ A,
                                               const float* __restrict__ C,
                                               float* __restrict__ out) {
  __shared__ float tile[32][33];
  int b = blockIdx.z;
  int n0 = blockIdx.x * 32;
  int c0 = blockIdx.y * 32;
  int tx = threadIdx.x, ty = threadIdx.y;
  float a = A[c0 + tx], cc = C[c0 + tx];
  for (int r = ty; r < 32; r += 8) {
    float v = o2[(size_t)(b * 16384 + n0 + r) * 128 + c0 + tx];
    tile[r][tx] = fmaxf(fmaf(a, v, cc), 0.f);
  }
  __syncthreads();
  for (int r = ty; r < 32; r += 8)
    out[((size_t)(b * 128 + c0 + r)) * 16384 + n0 + tx] = tile[tx][r];
}

extern "C" void kernel_launch(void* const* d_in, const int* in_sizes, int n_in,
                              void* d_out, int out_size, void* d_ws, size_t ws_size,
                              hipStream_t stream) {
  const float* xyz1 = (const float*)d_in[0];
  const float* xyz2 = (const float*)d_in[1];
  const float* p1   = (const float*)d_in[2];
  const float* p2   = (const float*)d_in[3];
  const int*   idx1 = (const int*)d_in[4];
  const int*   idx2 = (const int*)d_in[5];
  const float* w1   = (const float*)d_in[6];
  // d_in[7]=b1, d_in[11]=b2: exactly absorbed by BN mean subtraction
  const float* g1   = (const float*)d_in[8];
  const float* be1  = (const float*)d_in[9];
  const float* w2   = (const float*)d_in[10];
  const float* g2   = (const float*)d_in[12];
  const float* be2  = (const float*)d_in[13];
  float* out = (float*)d_out;

  char* ws = (char*)d_ws;
  // idx3 | wgt | X 48MB | h1T 32MB (p2t bf16 8.4MB aliased, dead before
  // gemm1 writes) | o2 32MB (rec 25.2MB aliased, dead before gemm2 writes)
  // | w1b w2b part1 part2 params  => ~114MB
  int*            idx3 = (int*)(ws + 0x0);                      // 0.75MB
  float*          wgt  = (float*)(ws + 0xC0000);                // 0.75MB
  unsigned short* X    = (unsigned short*)(ws + 0x180000);      // 48MB
  unsigned short* h1T  = (unsigned short*)(ws + 0x3180000);     // 32MB
  unsigned short* p2t  = (unsigned short*)(ws + 0x3180000);     // alias h1T
  float*          o2   = (float*)(ws + 0x5180000);              // 32MB
  float*          rec  = (float*)(ws + 0x5180000);              // alias o2
  unsigned short* w1b  = (unsigned short*)(ws + 0x7180000);
  unsigned short* w2b  = (unsigned short*)(ws + 0x71B0000);
  float*          part1 = (float*)(ws + 0x71C0000);
  float*          part2 = (float*)(ws + 0x7240000);
  float*          a1   = (float*)(ws + 0x7280000);
  float*          c1   = a1 + 256;
  float*          a2   = c1 + 256;
  float*          c2   = a2 + 128;

  hipLaunchKernelGGL(transpose_k, dim3(128, 8, 4), dim3(32, 8), 0, stream, p2, p2t);
  hipLaunchKernelGGL(wcvt_k, dim3(512), dim3(256), 0, stream, w1, w2, w1b, w2b);
  hipLaunchKernelGGL(p1t_k, dim3(512, 4, 4), dim3(32, 8), 0, stream, p1, X);
  hipLaunchKernelGGL(knn_k, dim3(1024), dim3(256), 0, stream,
                     xyz1, xyz2, idx1, idx2, rec);
  hipLaunchKernelGGL(knnmerge_k, dim3(256), dim3(256), 0, stream, rec, idx3, wgt);
  hipLaunchKernelGGL(interp_k, dim3(512), dim3(256), 0, stream, p2t, idx3, wgt, X);
  hipLaunchKernelGGL(gemm1_k, dim3(512, 2), dim3(256), 0, stream, X, w1b, h1T);
  hipLaunchKernelGGL(bnstats1_k, dim3(256), dim3(256), 0, stream, h1T, part1);
  hipLaunchKernelGGL((bnfold_k<256>), dim3(1), dim3(256), 0, stream, part1, g1, be1, a1, c1);
  hipLaunchKernelGGL(gemm2_k, dim3(512), dim3(256), 0, stream, h1T, w2b, a1, c1, o2);
  hipLaunchKernelGGL(bnstats2_k, dim3(256), dim3(256), 0, stream, o2, part2);
  hipLaunchKernelGGL((bnfold_k<128>), dim3(1), dim3(256), 0, stream, part2, g2, be2, a2, c2);
  hipLaunchKernelGGL(final_k, dim3(512, 4, 4), dim3(32, 8), 0, stream, o2, a2, c2, out);
}